// Round 21
// baseline (450.304 us; speedup 1.0000x reference)
//
#include <hip/hip_runtime.h>
#include <stdint.h>

#define PI_F      3.14159265358979323846f
#define TWO_PI_F  6.28318530717958647692f
#define DT_F      0.05f
#define DIFF_SCALE_F 0.3f

typedef short short8 __attribute__((ext_vector_type(8)));
typedef float f32x4 __attribute__((ext_vector_type(4)));
typedef float f32x2 __attribute__((ext_vector_type(2)));
typedef unsigned int u32x4 __attribute__((ext_vector_type(4)));
typedef unsigned int u32x2 __attribute__((ext_vector_type(2)));

__device__ __forceinline__ unsigned short f2bf(float x) {
    unsigned int u = __float_as_uint(x);
    u += 0x7FFFu + ((u >> 16) & 1u);
    return (unsigned short)(u >> 16);
}
__device__ __forceinline__ float bf2f(unsigned short h) {
    return __uint_as_float(((unsigned int)h) << 16);
}
__device__ __forceinline__ unsigned int cvtpk_bf16(float lo, float hi) {
    unsigned int r;
    asm("v_cvt_pk_bf16_f32 %0, %1, %2" : "=v"(r) : "v"(lo), "v"(hi));
    return r;
}
__device__ __forceinline__ float siluf(float x) {
    return x / (1.0f + __expf(-x));
}
__device__ __forceinline__ float wrapf(float t) {
    float w = fmodf(t + PI_F, TWO_PI_F);
    w = (w < 0.0f) ? w + TWO_PI_F : w;
    return w - PI_F;
}
__device__ __forceinline__ float dot4(const float* __restrict__ W, const float* __restrict__ X, int K) {
    float a = 0.0f;
#pragma unroll 4
    for (int kk = 0; kk < K; kk += 4) {
        f32x4 wv = *(const f32x4*)(W + kk);
        f32x4 xv = *(const f32x4*)(X + kk);
        a += wv[0]*xv[0] + wv[1]*xv[1] + wv[2]*xv[2] + wv[3]*xv[3];
    }
    return a;
}

#define SYNC_RAW() do { \
    asm volatile("s_waitcnt lgkmcnt(0)" ::: "memory"); \
    __builtin_amdgcn_s_barrier(); \
    __builtin_amdgcn_sched_barrier(0); \
} while (0)

// ---------------- K0: pack wih into MFMA-fragment order; whh row-major bf16 ----------------
__global__ void prep_kernel(const float* __restrict__ wih, const float* __restrict__ whh,
                            unsigned short* __restrict__ wihp, unsigned short* __restrict__ whhb) {
    int i = blockIdx.x * 256 + threadIdx.x;
    if (i < 196608) {
        int e = i & 7, lane = (i >> 3) & 63, rest = i >> 9;
        int ns = rest % 6, ki = (rest / 6) & 1, half = (rest / 12) & 1;
        int dt = (rest / 24) & 3, w = rest / 96;
        int col = w*96 + ns*16 + (lane & 15);
        int k   = half*256 + dt*64 + ki*32 + (lane >> 4)*8 + e;
        wihp[i] = f2bf(wih[col*512 + k]);
    }
    if (i < 384*128) whhb[i] = f2bf(whh[i]);
}

// ---------------- K0b: pack SDE MLP weights into fragment order (into dead P01 region) ----------------
__global__ void prep2_kernel(const float* __restrict__ dr_w0, const float* __restrict__ dr_w1,
                             const float* __restrict__ dr_w2, const float* __restrict__ dr_w3,
                             const float* __restrict__ df_w0, const float* __restrict__ df_w1,
                             const float* __restrict__ df_w2,
                             unsigned short* __restrict__ dst) {
    int i = blockIdx.x * 256 + threadIdx.x;   // 0..262143
    int e = i & 7, lane = (i >> 3) & 63;
    int l15 = lane & 15, l4 = lane >> 4;
    const float* src; int base, K, wide;
    if      (i < 73728)  { src = dr_w0; base = 0;      K = 576; wide = 0; }
    else if (i < 90112)  { src = dr_w1; base = 73728;  K = 128; wide = 0; }
    else if (i < 106496) { src = dr_w2; base = 90112;  K = 128; wide = 0; }
    else if (i < 139264) { src = dr_w3; base = 106496; K = 128; wide = 1; }
    else if (i < 212992) { src = df_w0; base = 139264; K = 576; wide = 0; }
    else if (i < 229376) { src = df_w1; base = 212992; K = 128; wide = 0; }
    else                 { src = df_w2; base = 229376; K = 128; wide = 1; }
    int lr = (i - base) >> 9;
    int nks = (K == 576) ? 18 : 4;
    int j, k;
    if (!wide) {
        int w = lr / nks, ks = lr % nks;
        j = w*16 + l15;
        k = ks*32 + l4*8 + e;
    } else {
        int ks = lr & 3, tile = (lr >> 2) & 1, w = lr >> 3;
        j = w*32 + tile*16 + l15;
        k = ks*32 + l4*8 + e;
    }
    dst[i] = f2bf(src[(size_t)j*K + k]);
}

// ---------------- K1: gi = [sin|cos](context) @ wih^T  (producer/consumer waves, BM=32) ----------------
// Waves 0-3 PRODUCE: ctx global->reg (prefetched 1 phase ahead, per-wave vmem queue),
// sin/cos via cvt_pk, write swizzled As double-buffer. Waves 4-7 CONSUME: As fragments +
// L2-hot packed bF -> 24 MFMAs/phase. 5 barrier phases pipeline dt; NO global_load_lds,
// NO vmcnt drains. LDS 40KB, launch_bounds(512,2): VGPR cap 128 (consumer ~110, no spill).
__launch_bounds__(512, 2)
__global__ void gi_gemm_kernel(const float* __restrict__ ctx_ang,
                               const unsigned short* __restrict__ wihp,
                               unsigned int* __restrict__ P01,
                               unsigned short* __restrict__ P2) {
    __shared__ __align__(16) unsigned short As[2][2][32*64];  // [buf][sin/cos][row*64+d], 16 KB
    __shared__ __align__(16) char stg[24576];                 // epilogue staging, 24 KB

    const int tid  = threadIdx.x;
    const int lane = tid & 63;
    const int wv   = tid >> 6;       // wave 0..7
    const bool isProd = (wv < 4);
    const int l15  = lane & 15;
    const int l4   = lane >> 4;
    const int mt   = blockIdx.x;     // 0..8191
    const int t    = mt >> 5;
    const int b0   = (mt & 31) * 32;

    // producer indexing: thread p=tid (0..255) -> row p>>3, d-granule p&7
    const int prow = tid >> 3;       // 0..31 (valid for producers)
    const int pseg = tid & 7;        // 0..7
    const float* psrc0 = ctx_ang + ((size_t)(b0 + prow) * 65536 + (size_t)t * 256 + pseg * 8);

    // consumer indexing
    const int w2 = wv - 4;           // 0..3, col base w2*96

    f32x4 acc[2][6];
    const f32x4 z4 = {0.0f, 0.0f, 0.0f, 0.0f};
#pragma unroll
    for (int mi = 0; mi < 2; ++mi)
#pragma unroll
        for (int ns = 0; ns < 6; ++ns) acc[mi][ns] = z4;

    f32x4 ra[2], rb[2];
#define PLOAD(slot, dt_) do { \
    ra[slot] = *(const f32x4*)(psrc0 + (dt_)*64); \
    rb[slot] = *(const f32x4*)(psrc0 + (dt_)*64 + 4); \
} while (0)

#define PPROC(slot, buf_) do { \
    f32x4 _a = ra[slot], _b = rb[slot]; \
    unsigned int s0 = cvtpk_bf16(__sinf(_a[0]), __sinf(_a[1])); \
    unsigned int s1 = cvtpk_bf16(__sinf(_a[2]), __sinf(_a[3])); \
    unsigned int s2 = cvtpk_bf16(__sinf(_b[0]), __sinf(_b[1])); \
    unsigned int s3 = cvtpk_bf16(__sinf(_b[2]), __sinf(_b[3])); \
    unsigned int c0 = cvtpk_bf16(__cosf(_a[0]), __cosf(_a[1])); \
    unsigned int c1 = cvtpk_bf16(__cosf(_a[2]), __cosf(_a[3])); \
    unsigned int c2 = cvtpk_bf16(__cosf(_b[0]), __cosf(_b[1])); \
    unsigned int c3 = cvtpk_bf16(__cosf(_b[2]), __cosf(_b[3])); \
    int boff = prow*128 + ((pseg ^ (prow & 7)) * 16); \
    u32x4 sv = { s0, s1, s2, s3 }; \
    u32x4 cc = { c0, c1, c2, c3 }; \
    *(u32x4*)((char*)&As[buf_][0][0] + boff) = sv; \
    *(u32x4*)((char*)&As[buf_][1][0] + boff) = cc; \
} while (0)

#define CMFMA(dt_, buf_) do { \
    _Pragma("unroll") \
    for (int half = 0; half < 2; ++half) { \
        const char* Ab = (const char*)&As[buf_][half][0]; \
        _Pragma("unroll") \
        for (int ki = 0; ki < 2; ++ki) { \
            short8 aF[2], bF[6]; \
            _Pragma("unroll") \
            for (int mi = 0; mi < 2; ++mi) { \
                int row = mi*16 + l15; \
                int kg  = ki*4 + l4; \
                aF[mi] = *(const short8*)(Ab + row*128 + ((kg ^ (row & 7)))*16); \
            } \
            _Pragma("unroll") \
            for (int ns = 0; ns < 6; ++ns) { \
                int fidx = (((w2*4 + (dt_))*2 + half)*2 + ki)*6 + ns; \
                bF[ns] = *(const short8*)(wihp + ((size_t)fidx*64 + lane)*8); \
            } \
            _Pragma("unroll") \
            for (int mi = 0; mi < 2; ++mi) \
                _Pragma("unroll") \
                for (int ns = 0; ns < 6; ++ns) \
                    acc[mi][ns] = __builtin_amdgcn_mfma_f32_16x16x32_bf16(aF[mi], bF[ns], acc[mi][ns], 0, 0, 0); \
        } \
    } \
} while (0)

    if (isProd) PLOAD(0, 0);

    // 5 phases: producers fill As[p&1] with dt=p (p<4); consumers MFMA As[(p-1)&1] dt=p-1 (p>=1)
#pragma unroll
    for (int p = 0; p < 5; ++p) {
        if (p < 4 && isProd) {
            if (p < 3) PLOAD((p + 1) & 1, p + 1);
            PPROC(p & 1, p & 1);
        }
        if (p >= 1 && !isProd) {
            CMFMA(p - 1, (p - 1) & 1);
        }
        SYNC_RAW();
    }

    // ---- epilogue: consumers stage acc (S01 16KB | S2 8KB); all 512 threads store ----
    if (!isProd) {
#pragma unroll
        for (int mi = 0; mi < 2; ++mi) {
#pragma unroll
            for (int ns = 0; ns < 6; ++ns) {
                int col = w2*96 + ns*16 + l15;
                int g = col >> 7, j = col & 127;   // g wave-uniform per tile
#pragma unroll
                for (int r = 0; r < 4; ++r) {
                    int b = mi*16 + l4*4 + r;      // local row 0..31
                    unsigned short vvv = f2bf(acc[mi][ns][r]);
                    if (g < 2) *(unsigned short*)(stg + ((size_t)(b*128 + j))*4 + g*2) = vvv;
                    else       *(unsigned short*)(stg + 16384 + ((size_t)(b*128 + j))*2) = vvv;
                }
            }
        }
    }
    SYNC_RAW();
    {
        const u32x4* s01v = (const u32x4*)stg;
        u32x4* dst01 = (u32x4*)(P01 + ((size_t)t*1024 + b0)*128);
#pragma unroll
        for (int e = 0; e < 2; ++e)
            dst01[tid + e*512] = s01v[tid + e*512];
        const u32x4* s2v = (const u32x4*)(stg + 16384);
        u32x4* dst2 = (u32x4*)(P2 + ((size_t)t*1024 + b0)*128);
        dst2[tid] = s2v[tid];
    }
#undef PLOAD
#undef PPROC
#undef CMFMA
}

// ---------------- K2: GRU scan v6 — batch rows at 0,4,8,12; gates in-lane; ONE barrier/step ----------------

#define LOADPF(PA, PB, tt) do { \
    if ((tt) < 256) { \
        size_t _i = ((size_t)(tt)*1024 + b0 + l4)*128 + j; \
        PA = P01[_i]; \
        PB = P2[_i]; \
    } \
} while (0)

#define STEP(RDBUF, WRBUF, PA, PB, TT) do { \
    short8 aF[4]; \
    _Pragma("unroll") \
    for (int kt = 0; kt < 4; ++kt) \
        aF[kt] = *(const short8*)((const char*)(RDBUF) + l15*256 + (((kt*4 + l4) ^ (l15 & 7)))*16); \
    f32x4 q0[4], q1[4], q2[4]; \
    _Pragma("unroll") \
    for (int kt = 0; kt < 4; ++kt) { \
        q0[kt] = __builtin_amdgcn_mfma_f32_16x16x32_bf16(aF[kt], whB0[kt], z4, 0, 0, 0); \
        q1[kt] = __builtin_amdgcn_mfma_f32_16x16x32_bf16(aF[kt], whB1[kt], z4, 0, 0, 0); \
        q2[kt] = __builtin_amdgcn_mfma_f32_16x16x32_bf16(aF[kt], whB2[kt], z4, 0, 0, 0); \
    } \
    float g0 = (q0[0][0] + q0[1][0]) + (q0[2][0] + q0[3][0]); \
    float g1 = (q1[0][0] + q1[1][0]) + (q1[2][0] + q1[3][0]); \
    float g2 = (q2[0][0] + q2[1][0]) + (q2[2][0] + q2[3][0]); \
    unsigned int _pa = PA; unsigned short _pb = PB; \
    LOADPF(PA, PB, TT); \
    { \
        float ir  = bf2f((unsigned short)(_pa & 0xFFFFu)) + bR; \
        float iz  = bf2f((unsigned short)(_pa >> 16))     + bZ; \
        float in_ = bf2f(_pb)                             + bN; \
        float rg = __builtin_amdgcn_rcpf(1.0f + __expf(-(ir + g0))); \
        float zg = __builtin_amdgcn_rcpf(1.0f + __expf(-(iz + g1))); \
        float ng = 1.0f - 2.0f*__builtin_amdgcn_rcpf(1.0f + __expf(2.0f*(in_ + rg*(g2 + bBN)))); \
        H = ng + zg*(H - ng); \
        int row = l4*4; \
        *(unsigned short*)((char*)(WRBUF) + row*256 + (((j >> 3) ^ (row & 7))*16) + (j & 7)*2) = f2bf(H); \
    } \
    SYNC_RAW(); \
} while (0)

__launch_bounds__(512, 4)
__global__ void scan_kernel(const unsigned int* __restrict__ P01,
                            const unsigned short* __restrict__ P2,
                            const unsigned short* __restrict__ whhb,
                            const float* __restrict__ gru_b,
                            const float* __restrict__ gru_bn,
                            float* __restrict__ h_ws) {
    __shared__ __align__(16) unsigned short hAbuf[2][16*128];  // rows 0,4,8,12 live; rest zero

    const int tid  = threadIdx.x;
    const int lane = tid & 63;
    const int w    = tid >> 6;           // wave 0..7, owns cols w*16..w*16+15
    const int l15  = lane & 15;
    const int l4   = lane >> 4;          // batch 0..3 (gate role)
    const int b0   = blockIdx.x * 4;     // batches b0..b0+3
    const int j    = w*16 + l15;         // hidden col (MFMA N-col AND gate col)

    {
        u32x4 z = {0u,0u,0u,0u};
        *(u32x4*)((char*)hAbuf + tid*16) = z;
    }

    short8 whB0[4], whB1[4], whB2[4];
#pragma unroll
    for (int kt = 0; kt < 4; ++kt) {
        whB0[kt] = *(const short8*)(whhb + (size_t)(0*128 + j)*128 + kt*32 + l4*8);
        whB1[kt] = *(const short8*)(whhb + (size_t)(1*128 + j)*128 + kt*32 + l4*8);
        whB2[kt] = *(const short8*)(whhb + (size_t)(2*128 + j)*128 + kt*32 + l4*8);
    }
    const float bR  = gru_b[j];
    const float bZ  = gru_b[128 + j];
    const float bN  = gru_b[256 + j];
    const float bBN = gru_bn[j];

    float H = 0.f;
    const f32x4 z4 = {0.0f,0.0f,0.0f,0.0f};

    unsigned int  PAa = 0, PAb = 0, PAc = 0, PAd = 0;
    unsigned short PBa = 0, PBb = 0, PBc = 0, PBd = 0;
    LOADPF(PAa, PBa, 0);
    LOADPF(PAb, PBb, 1);
    LOADPF(PAc, PBc, 2);
    LOADPF(PAd, PBd, 3);
    __syncthreads();

    for (int t = 0; t < 256; t += 4) {
        STEP(&hAbuf[0][0], &hAbuf[1][0], PAa, PBa, t + 4);
        STEP(&hAbuf[1][0], &hAbuf[0][0], PAb, PBb, t + 5);
        STEP(&hAbuf[0][0], &hAbuf[1][0], PAc, PBc, t + 6);
        STEP(&hAbuf[1][0], &hAbuf[0][0], PAd, PBd, t + 7);
    }

    h_ws[(size_t)(b0 + l4)*128 + j] = H;
}

// ---------------- K3: proj + SDE, MFMA, 4 batches/block x 256 blocks (all CUs) ----------------
#define AFRAG(BUF, S, ks) (*(const short8*)((const char*)(BUF) + l15*(S) + ((((ks)*4 + l4) ^ (l15 & 7))*16)))
#define PF18(W, ks) (*(const short8*)((W) + (((size_t)(w*18 + (ks)))*64 + lane)*8))
#define PF4(W, ks)  (*(const short8*)((W) + (((size_t)(w*4 + (ks)))*64 + lane)*8))
#define PFW(W, tile, ks) (*(const short8*)((W) + (((size_t)((w*2 + (tile))*4 + (ks)))*64 + lane)*8))
#define HSTORE(BUF, bb, col, val) (*(unsigned short*)((char*)(BUF) + (bb)*256 + ((((col)>>3) ^ ((bb)&7))*16) + ((col)&7)*2) = f2bf(val))
#define MFMA16(af, bf, c) __builtin_amdgcn_mfma_f32_16x16x32_bf16((af), (bf), (c), 0, 0, 0)

__launch_bounds__(512, 1)
__global__ void sde_kernel(const float* __restrict__ ctx_ang,
                           const float* __restrict__ dW,
                           const float* __restrict__ proj_w,
                           const float* __restrict__ proj_b,
                           const float* __restrict__ dr_b0, const float* __restrict__ dr_b1,
                           const float* __restrict__ dr_b2, const float* __restrict__ dr_b3,
                           const float* __restrict__ df_b0, const float* __restrict__ df_b1,
                           const float* __restrict__ df_b2,
                           const unsigned short* __restrict__ W0d, const unsigned short* __restrict__ W1d,
                           const unsigned short* __restrict__ W2d, const unsigned short* __restrict__ W3d,
                           const unsigned short* __restrict__ W0f, const unsigned short* __restrict__ W1f,
                           const unsigned short* __restrict__ W2f,
                           const float* __restrict__ h_ws,
                           float* __restrict__ out) {
    __shared__ __align__(16) float th[4*256];
    __shared__ __align__(16) float ctxs[4*64];
    __shared__ __align__(16) float h32[4*128];
    __shared__ __align__(16) unsigned short inpA[16*576];
    __shared__ __align__(16) unsigned short hA[16*128], hB[16*128], hC[16*128], hD[16*128];

    const int tid  = threadIdx.x;
    const int lane = tid & 63;
    const int w    = tid >> 6;
    const int l15  = lane & 15;
    const int l4   = lane >> 4;
    const int b0   = blockIdx.x * 4;
    const f32x4 z4 = {0.f,0.f,0.f,0.f};

    h32[tid & 511] = 0.0f;
    __syncthreads();
    ((float*)h32)[tid] = h_ws[(size_t)b0*128 + tid];
    __syncthreads();
    if (tid < 256) {
        int b = tid >> 6, c = tid & 63;
        ctxs[tid] = proj_b[c] + dot4(proj_w + (size_t)c*128, h32 + b*128, 128);
    }
#pragma unroll
    for (int e = 0; e < 2; ++e) {
        int idx = tid + e*512; int b = idx >> 8, i = idx & 255;
        th[idx] = wrapf(ctx_ang[((size_t)(b0 + b)*256 + 255)*256 + i]);
    }

    const int j  = w*16 + l15;
    const int j20 = w*32 + l15;
    const int j21 = w*32 + 16 + l15;
    const float bd0 = dr_b0[j], bd1 = dr_b1[j], bd2 = dr_b2[j];
    const float bf0 = df_b0[j], bf1 = df_b1[j];
    const float bd3t0 = dr_b3[j20], bd3t1 = dr_b3[j21];
    const float bf2t0 = df_b2[j20], bf2t1 = df_b2[j21];
    __syncthreads();

    for (int k = 0; k < 5; ++k) {
#pragma unroll
        for (int e = 0; e < 5; ++e) {
            int idx = tid + e*512;
            if (idx < 2304) {
                int b = idx / 576;
                int i = idx - b*576;
                float vv;
                if (i < 256)      vv = __sinf(th[(b<<8) + i]);
                else if (i < 512) vv = __cosf(th[(b<<8) + i - 256]);
                else              vv = ctxs[(b<<6) + i - 512];
                *(unsigned short*)((char*)inpA + b*1152 + (((i>>3) ^ (b&7))*16) + (i&7)*2) = f2bf(vv);
            }
        }
        __syncthreads();

        // p1: drift L0 || diff L0, K=576
        {
            f32x4 a0=z4,a1=z4,c0=z4,c1=z4;
#pragma unroll
            for (int ks = 0; ks < 18; ks += 2) {
                short8 af0 = AFRAG(inpA, 1152, ks);
                short8 af1 = AFRAG(inpA, 1152, ks+1);
                a0 = MFMA16(af0, PF18(W0d, ks),   a0);
                c0 = MFMA16(af0, PF18(W0f, ks),   c0);
                a1 = MFMA16(af1, PF18(W0d, ks+1), a1);
                c1 = MFMA16(af1, PF18(W0f, ks+1), c1);
            }
#pragma unroll
            for (int r = 0; r < 4; ++r) {
                int bb = l4*4 + r;
                HSTORE(hA, bb, j, siluf(a0[r] + a1[r] + bd0));
                HSTORE(hC, bb, j, siluf(c0[r] + c1[r] + bf0));
            }
        }
        __syncthreads();

        // p2: drift L1 || diff L1, K=128
        {
            f32x4 a0=z4,a1=z4,c0=z4,c1=z4;
#pragma unroll
            for (int ks = 0; ks < 4; ks += 2) {
                short8 aA0 = AFRAG(hA, 256, ks), aA1 = AFRAG(hA, 256, ks+1);
                short8 aC0 = AFRAG(hC, 256, ks), aC1 = AFRAG(hC, 256, ks+1);
                a0 = MFMA16(aA0, PF4(W1d, ks),   a0);
                c0 = MFMA16(aC0, PF4(W1f, ks),   c0);
                a1 = MFMA16(aA1, PF4(W1d, ks+1), a1);
                c1 = MFMA16(aC1, PF4(W1f, ks+1), c1);
            }
#pragma unroll
            for (int r = 0; r < 4; ++r) {
                int bb = l4*4 + r;
                HSTORE(hB, bb, j, siluf(a0[r] + a1[r] + bd1));
                HSTORE(hD, bb, j, siluf(c0[r] + c1[r] + bf1));
            }
        }
        __syncthreads();

        // p3: drift L2 || diff L2 (N=256), K=128; sg kept in REGISTERS
        float sgr[2][4];
        {
            f32x4 a0=z4,a1=z4,s0=z4,s1=z4,s2=z4,s3=z4;
#pragma unroll
            for (int ks = 0; ks < 4; ks += 2) {
                short8 b0f = AFRAG(hB, 256, ks), b1f = AFRAG(hB, 256, ks+1);
                short8 d0f = AFRAG(hD, 256, ks), d1f = AFRAG(hD, 256, ks+1);
                a0 = MFMA16(b0f, PF4(W2d, ks),   a0);
                a1 = MFMA16(b1f, PF4(W2d, ks+1), a1);
                s0 = MFMA16(d0f, PFW(W2f, 0, ks),   s0);
                s1 = MFMA16(d1f, PFW(W2f, 0, ks+1), s1);
                s2 = MFMA16(d0f, PFW(W2f, 1, ks),   s2);
                s3 = MFMA16(d1f, PFW(W2f, 1, ks+1), s3);
            }
#pragma unroll
            for (int r = 0; r < 4; ++r) {
                int bb = l4*4 + r;
                HSTORE(hA, bb, j, siluf(a0[r] + a1[r] + bd2));
                float aa0 = s0[r] + s1[r] + bf2t0;
                float aa1 = s2[r] + s3[r] + bf2t1;
                float sp0 = (aa0 > 15.f) ? aa0 : log1pf(__expf(aa0));
                float sp1 = (aa1 > 15.f) ? aa1 : log1pf(__expf(aa1));
                sgr[0][r] = sp0 * DIFF_SCALE_F;
                sgr[1][r] = sp1 * DIFF_SCALE_F;
            }
        }
        __syncthreads();

        // p4: drift L3 (N=256), K=128; theta update (only l4==0 lanes own valid rows 0-3)
        {
            f32x4 m0=z4,m1=z4,m2=z4,m3=z4;
#pragma unroll
            for (int ks = 0; ks < 4; ks += 2) {
                short8 h0f = AFRAG(hA, 256, ks), h1f = AFRAG(hA, 256, ks+1);
                m0 = MFMA16(h0f, PFW(W3d, 0, ks),   m0);
                m1 = MFMA16(h1f, PFW(W3d, 0, ks+1), m1);
                m2 = MFMA16(h0f, PFW(W3d, 1, ks),   m2);
                m3 = MFMA16(h1f, PFW(W3d, 1, ks+1), m3);
            }
            if (l4 == 0) {
#pragma unroll
                for (int r = 0; r < 4; ++r) {
                    int bb = r;
                    {
                        float mu = m0[r] + m1[r] + bd3t0;
                        float dw = dW[((size_t)(b0 + bb)*5 + k)*256 + j20];
                        th[(bb<<8) + j20] = wrapf(th[(bb<<8) + j20] + mu*DT_F + sgr[0][r]*dw);
                    }
                    {
                        float mu = m2[r] + m3[r] + bd3t1;
                        float dw = dW[((size_t)(b0 + bb)*5 + k)*256 + j21];
                        th[(bb<<8) + j21] = wrapf(th[(bb<<8) + j21] + mu*DT_F + sgr[1][r]*dw);
                    }
                }
            }
        }
        __syncthreads();
    }

#pragma unroll
    for (int e = 0; e < 2; ++e) {
        int idx = tid + e*512;
        out[(size_t)b0*256 + idx] = th[idx];
    }
}

extern "C" void kernel_launch(void* const* d_in, const int* in_sizes, int n_in,
                              void* d_out, int out_size, void* d_ws, size_t ws_size,
                              hipStream_t stream) {
    const float* ctx_ang = (const float*)d_in[0];
    const float* dW      = (const float*)d_in[1];
    const float* wih     = (const float*)d_in[2];
    const float* whh     = (const float*)d_in[3];
    const float* gru_b   = (const float*)d_in[4];
    const float* gru_bn  = (const float*)d_in[5];
    const float* proj_w  = (const float*)d_in[6];
    const float* proj_b  = (const float*)d_in[7];
    const float* dr_w0   = (const float*)d_in[8];
    const float* dr_b0   = (const float*)d_in[9];
    const float* dr_w1   = (const float*)d_in[10];
    const float* dr_b1   = (const float*)d_in[11];
    const float* dr_w2   = (const float*)d_in[12];
    const float* dr_b2   = (const float*)d_in[13];
    const float* dr_w3   = (const float*)d_in[14];
    const float* dr_b3   = (const float*)d_in[15];
    const float* df_w0   = (const float*)d_in[16];
    const float* df_b0   = (const float*)d_in[17];
    const float* df_w1   = (const float*)d_in[18];
    const float* df_b1   = (const float*)d_in[19];
    const float* df_w2   = (const float*)d_in[20];
    const float* df_b2   = (const float*)d_in[21];
    float* out = (float*)d_out;

    char* ws = (char*)d_ws;
    unsigned int*   P01  = (unsigned int*)ws;                         // 134,217,728 B
    unsigned short* P2   = (unsigned short*)(ws + 134217728);         //  67,108,864 B
    unsigned short* wihp = (unsigned short*)(ws + 201326592);         //     393,216 B (packed)
    unsigned short* whhb = (unsigned short*)(ws + 201719808);         //      98,304 B
    float*          h_ws = (float*)(ws + 201818112);                  //     524,288 B

    unsigned short* Wb  = (unsigned short*)ws;   // dead P01 region after scan
    unsigned short* W0d = Wb;
    unsigned short* W1d = Wb + 73728;
    unsigned short* W2d = Wb + 90112;
    unsigned short* W3d = Wb + 106496;
    unsigned short* W0f = Wb + 139264;
    unsigned short* W1f = Wb + 212992;
    unsigned short* W2f = Wb + 229376;

    prep_kernel<<<768, 256, 0, stream>>>(wih, whh, wihp, whhb);
    gi_gemm_kernel<<<8192, 512, 0, stream>>>(ctx_ang, wihp, P01, P2);
    scan_kernel<<<256, 512, 0, stream>>>(P01, P2, whhb, gru_b, gru_bn, h_ws);
    prep2_kernel<<<1024, 256, 0, stream>>>(dr_w0, dr_w1, dr_w2, dr_w3, df_w0, df_w1, df_w2, Wb);
    sde_kernel<<<256, 512, 0, stream>>>(ctx_ang, dW,
        proj_w, proj_b, dr_b0, dr_b1, dr_b2, dr_b3, df_b0, df_b1, df_b2,
        W0d, W1d, W2d, W3d, W0f, W1f, W2f, h_ws, out);
}

// Round 22
// 398.880 us; speedup vs baseline: 1.1289x; 1.1289x over previous
//
#include <hip/hip_runtime.h>
#include <stdint.h>

#define PI_F      3.14159265358979323846f
#define TWO_PI_F  6.28318530717958647692f
#define DT_F      0.05f
#define DIFF_SCALE_F 0.3f

typedef short short8 __attribute__((ext_vector_type(8)));
typedef float f32x4 __attribute__((ext_vector_type(4)));
typedef float f32x2 __attribute__((ext_vector_type(2)));
typedef unsigned int u32x4 __attribute__((ext_vector_type(4)));
typedef unsigned int u32x2 __attribute__((ext_vector_type(2)));

__device__ __forceinline__ unsigned short f2bf(float x) {
    unsigned int u = __float_as_uint(x);
    u += 0x7FFFu + ((u >> 16) & 1u);
    return (unsigned short)(u >> 16);
}
__device__ __forceinline__ float bf2f(unsigned short h) {
    return __uint_as_float(((unsigned int)h) << 16);
}
__device__ __forceinline__ unsigned int cvtpk_bf16(float lo, float hi) {
    unsigned int r;
    asm("v_cvt_pk_bf16_f32 %0, %1, %2" : "=v"(r) : "v"(lo), "v"(hi));
    return r;
}
__device__ __forceinline__ float siluf(float x) {
    return x / (1.0f + __expf(-x));
}
__device__ __forceinline__ float wrapf(float t) {
    float w = fmodf(t + PI_F, TWO_PI_F);
    w = (w < 0.0f) ? w + TWO_PI_F : w;
    return w - PI_F;
}
__device__ __forceinline__ float dot4(const float* __restrict__ W, const float* __restrict__ X, int K) {
    float a = 0.0f;
#pragma unroll 4
    for (int kk = 0; kk < K; kk += 4) {
        f32x4 wv = *(const f32x4*)(W + kk);
        f32x4 xv = *(const f32x4*)(X + kk);
        a += wv[0]*xv[0] + wv[1]*xv[1] + wv[2]*xv[2] + wv[3]*xv[3];
    }
    return a;
}

#define SYNC_RAW() do { \
    asm volatile("s_waitcnt lgkmcnt(0)" ::: "memory"); \
    __builtin_amdgcn_s_barrier(); \
    __builtin_amdgcn_sched_barrier(0); \
} while (0)

// ---------------- K0: pack wih into MFMA-fragment order; whh row-major bf16 ----------------
__global__ void prep_kernel(const float* __restrict__ wih, const float* __restrict__ whh,
                            unsigned short* __restrict__ wihp, unsigned short* __restrict__ whhb) {
    int i = blockIdx.x * 256 + threadIdx.x;
    if (i < 196608) {
        int e = i & 7, lane = (i >> 3) & 63, rest = i >> 9;
        int ns = rest % 6, ki = (rest / 6) & 1, half = (rest / 12) & 1;
        int dt = (rest / 24) & 3, w = rest / 96;
        int col = w*96 + ns*16 + (lane & 15);
        int k   = half*256 + dt*64 + ki*32 + (lane >> 4)*8 + e;
        wihp[i] = f2bf(wih[col*512 + k]);
    }
    if (i < 384*128) whhb[i] = f2bf(whh[i]);
}

// ---------------- K0b: pack SDE MLP weights into fragment order (into dead P01 region) ----------------
__global__ void prep2_kernel(const float* __restrict__ dr_w0, const float* __restrict__ dr_w1,
                             const float* __restrict__ dr_w2, const float* __restrict__ dr_w3,
                             const float* __restrict__ df_w0, const float* __restrict__ df_w1,
                             const float* __restrict__ df_w2,
                             unsigned short* __restrict__ dst) {
    int i = blockIdx.x * 256 + threadIdx.x;   // 0..262143
    int e = i & 7, lane = (i >> 3) & 63;
    int l15 = lane & 15, l4 = lane >> 4;
    const float* src; int base, K, wide;
    if      (i < 73728)  { src = dr_w0; base = 0;      K = 576; wide = 0; }
    else if (i < 90112)  { src = dr_w1; base = 73728;  K = 128; wide = 0; }
    else if (i < 106496) { src = dr_w2; base = 90112;  K = 128; wide = 0; }
    else if (i < 139264) { src = dr_w3; base = 106496; K = 128; wide = 1; }
    else if (i < 212992) { src = df_w0; base = 139264; K = 576; wide = 0; }
    else if (i < 229376) { src = df_w1; base = 212992; K = 128; wide = 0; }
    else                 { src = df_w2; base = 229376; K = 128; wide = 1; }
    int lr = (i - base) >> 9;
    int nks = (K == 576) ? 18 : 4;
    int j, k;
    if (!wide) {
        int w = lr / nks, ks = lr % nks;
        j = w*16 + l15;
        k = ks*32 + l4*8 + e;
    } else {
        int ks = lr & 3, tile = (lr >> 2) & 1, w = lr >> 3;
        j = w*32 + tile*16 + l15;
        k = ks*32 + l4*8 + e;
    }
    dst[i] = f2bf(src[(size_t)j*K + k]);
}

// ---------------- K1: gi = [sin|cos](context) @ wih^T  (measured best: BM=32, 4 tiles upfront) ----------------
__launch_bounds__(256, 4)
__global__ void gi_gemm_kernel(const float* __restrict__ ctx_ang,
                               const unsigned short* __restrict__ wihp,
                               unsigned int* __restrict__ P01,
                               unsigned short* __restrict__ P2) {
    __shared__ __align__(16) float ctxL[4][32*64];          // 32 KB; reused as output staging
    __shared__ __align__(16) unsigned short As[2][32*64];   // 8 KB, swizzled

    const int tid  = threadIdx.x;
    const int lane = tid & 63;
    const int w    = tid >> 6;     // wave 0..3 (owns cols w*96..w*96+95)
    const int l15  = lane & 15;
    const int l4   = lane >> 4;
    const int mt   = blockIdx.x;   // 0..8191
    const int t    = mt >> 5;
    const int b0   = (mt & 31) * 32;

    const int l4r = lane >> 4;
    const int c4  = (lane & 15) * 4;

    f32x4 acc[2][6];
    const f32x4 z4 = {0.0f, 0.0f, 0.0f, 0.0f};
#pragma unroll
    for (int mi = 0; mi < 2; ++mi)
#pragma unroll
        for (int ns = 0; ns < 6; ++ns) acc[mi][ns] = z4;

    // issue all 4 ctx tiles (8 KB each): per wave 2 G2L instrs per tile
#pragma unroll
    for (int dt = 0; dt < 4; ++dt) {
#pragma unroll
        for (int i = 0; i < 2; ++i) {
            const float* src = ctx_ang + ((size_t)(b0 + w*8 + i*4 + l4r) * 65536
                                          + (size_t)t * 256 + dt*64 + c4);
            void* dst = (void*)((char*)&ctxL[dt][0] + (w*8 + i*4) * 256);
            __builtin_amdgcn_global_load_lds(
                (const __attribute__((address_space(1))) unsigned int*)src,
                (__attribute__((address_space(3))) unsigned int*)dst, 16, 0, 0);
        }
    }
    asm volatile("s_waitcnt vmcnt(0)" ::: "memory");
    __builtin_amdgcn_s_barrier();
    __builtin_amdgcn_sched_barrier(0);

#pragma unroll
    for (int dt = 0; dt < 4; ++dt) {
        // ---- S phase: ctxL[dt] fp32 -> sin/cos bf16 -> As (swizzled) ----
        {
            f32x4 cv[2];
#pragma unroll
            for (int r = 0; r < 2; ++r)
                cv[r] = *(const f32x4*)((const char*)&ctxL[dt][0] + tid*16 + r*4096);
#pragma unroll
            for (int r = 0; r < 2; ++r) {
                int row = (tid >> 4) + r*16;
                int c0  = (tid & 15) * 4;
                unsigned int s01 = cvtpk_bf16(__sinf(cv[r][0]), __sinf(cv[r][1]));
                unsigned int s23 = cvtpk_bf16(__sinf(cv[r][2]), __sinf(cv[r][3]));
                unsigned int c01 = cvtpk_bf16(__cosf(cv[r][0]), __cosf(cv[r][1]));
                unsigned int c23 = cvtpk_bf16(__cosf(cv[r][2]), __cosf(cv[r][3]));
                int boff = row*128 + (((c0 >> 3) ^ (row & 7)) * 16) + (c0 & 7) * 2;
                u32x2 sv = { s01, s23 };
                u32x2 cc = { c01, c23 };
                *(u32x2*)((char*)&As[0][0] + boff) = sv;
                *(u32x2*)((char*)&As[1][0] + boff) = cc;
            }
        }
        SYNC_RAW();   // As ready

        // ---- M phase: MFMA; packed bF wave-loads (L2-hot) ----
#pragma unroll
        for (int half = 0; half < 2; ++half) {
            const char* Ab = (const char*)&As[half][0];
#pragma unroll
            for (int ki = 0; ki < 2; ++ki) {
                short8 aF[2], bF[6];
#pragma unroll
                for (int mi = 0; mi < 2; ++mi) {
                    int row = mi*16 + l15;
                    int kg  = ki*4 + l4;
                    aF[mi] = *(const short8*)(Ab + row*128 + ((kg ^ (row & 7)))*16);
                }
#pragma unroll
                for (int ns = 0; ns < 6; ++ns) {
                    int fidx = (((w*4 + dt)*2 + half)*2 + ki)*6 + ns;
                    bF[ns] = *(const short8*)(wihp + ((size_t)fidx*64 + lane)*8);
                }
#pragma unroll
                for (int mi = 0; mi < 2; ++mi)
#pragma unroll
                    for (int ns = 0; ns < 6; ++ns)
                        acc[mi][ns] = __builtin_amdgcn_mfma_f32_16x16x32_bf16(aF[mi], bF[ns], acc[mi][ns], 0, 0, 0);
            }
        }
        SYNC_RAW();   // As reads drained before next S overwrites
    }

    // ---- epilogue: stage into dead ctxL region (S01 16KB | S2 8KB), then coalesced stores ----
    {
        char* stg = (char*)&ctxL[0][0];
#pragma unroll
        for (int mi = 0; mi < 2; ++mi) {
#pragma unroll
            for (int ns = 0; ns < 6; ++ns) {
                int col = w*96 + ns*16 + l15;
                int g = col >> 7, j = col & 127;   // g wave-uniform per tile
#pragma unroll
                for (int r = 0; r < 4; ++r) {
                    int b = mi*16 + l4*4 + r;      // local row 0..31
                    unsigned short vv = f2bf(acc[mi][ns][r]);
                    if (g < 2) *(unsigned short*)(stg + ((size_t)(b*128 + j))*4 + g*2) = vv;
                    else       *(unsigned short*)(stg + 16384 + ((size_t)(b*128 + j))*2) = vv;
                }
            }
        }
        SYNC_RAW();
        const u32x4* s01v = (const u32x4*)stg;
        u32x4* dst01 = (u32x4*)(P01 + ((size_t)t*1024 + b0)*128);
#pragma unroll
        for (int e = 0; e < 4; ++e)
            dst01[tid + e*256] = s01v[tid + e*256];
        const u32x4* s2v = (const u32x4*)(stg + 16384);
        u32x4* dst2 = (u32x4*)(P2 + ((size_t)t*1024 + b0)*128);
#pragma unroll
        for (int e = 0; e < 2; ++e)
            dst2[tid + e*256] = s2v[tid + e*256];
    }
}

// ---------------- K2: GRU scan (batch rows at 0,4,8,12; gates in-lane; ONE barrier/step) ----------------

#define LOADPF(PA, PB, tt) do { \
    if ((tt) < 256) { \
        size_t _i = ((size_t)(tt)*1024 + b0 + l4)*128 + j; \
        PA = P01[_i]; \
        PB = P2[_i]; \
    } \
} while (0)

#define STEP(RDBUF, WRBUF, PA, PB, TT) do { \
    short8 aF[4]; \
    _Pragma("unroll") \
    for (int kt = 0; kt < 4; ++kt) \
        aF[kt] = *(const short8*)((const char*)(RDBUF) + l15*256 + (((kt*4 + l4) ^ (l15 & 7)))*16); \
    f32x4 a0 = z4, a1 = z4, a2 = z4; \
    _Pragma("unroll") \
    for (int kt = 0; kt < 4; ++kt) { \
        a0 = __builtin_amdgcn_mfma_f32_16x16x32_bf16(aF[kt], whB0[kt], a0, 0, 0, 0); \
        a1 = __builtin_amdgcn_mfma_f32_16x16x32_bf16(aF[kt], whB1[kt], a1, 0, 0, 0); \
        a2 = __builtin_amdgcn_mfma_f32_16x16x32_bf16(aF[kt], whB2[kt], a2, 0, 0, 0); \
    } \
    unsigned int _pa = PA; unsigned short _pb = PB; \
    LOADPF(PA, PB, TT); \
    { \
        float ir  = bf2f((unsigned short)(_pa & 0xFFFFu)) + bR; \
        float iz  = bf2f((unsigned short)(_pa >> 16))     + bZ; \
        float in_ = bf2f(_pb)                             + bN; \
        float rg = __builtin_amdgcn_rcpf(1.0f + __expf(-(ir + a0[0]))); \
        float zg = __builtin_amdgcn_rcpf(1.0f + __expf(-(iz + a1[0]))); \
        float ng = 1.0f - 2.0f*__builtin_amdgcn_rcpf(1.0f + __expf(2.0f*(in_ + rg*(a2[0] + bBN)))); \
        H = ng + zg*(H - ng); \
        int row = l4*4; \
        *(unsigned short*)((char*)(WRBUF) + row*256 + (((j >> 3) ^ (row & 7))*16) + (j & 7)*2) = f2bf(H); \
    } \
    SYNC_RAW(); \
} while (0)

__launch_bounds__(512, 4)
__global__ void scan_kernel(const unsigned int* __restrict__ P01,
                            const unsigned short* __restrict__ P2,
                            const unsigned short* __restrict__ whhb,
                            const float* __restrict__ gru_b,
                            const float* __restrict__ gru_bn,
                            float* __restrict__ h_ws) {
    __shared__ __align__(16) unsigned short hAbuf[2][16*128];  // rows 0,4,8,12 live; rest zero

    const int tid  = threadIdx.x;
    const int lane = tid & 63;
    const int w    = tid >> 6;           // wave 0..7, owns cols w*16..w*16+15
    const int l15  = lane & 15;
    const int l4   = lane >> 4;          // batch 0..3 (gate role)
    const int b0   = blockIdx.x * 4;     // batches b0..b0+3
    const int j    = w*16 + l15;         // hidden col (MFMA N-col AND gate col)

    {
        u32x4 z = {0u,0u,0u,0u};
        *(u32x4*)((char*)hAbuf + tid*16) = z;
    }

    short8 whB0[4], whB1[4], whB2[4];
#pragma unroll
    for (int kt = 0; kt < 4; ++kt) {
        whB0[kt] = *(const short8*)(whhb + (size_t)(0*128 + j)*128 + kt*32 + l4*8);
        whB1[kt] = *(const short8*)(whhb + (size_t)(1*128 + j)*128 + kt*32 + l4*8);
        whB2[kt] = *(const short8*)(whhb + (size_t)(2*128 + j)*128 + kt*32 + l4*8);
    }
    const float bR  = gru_b[j];
    const float bZ  = gru_b[128 + j];
    const float bN  = gru_b[256 + j];
    const float bBN = gru_bn[j];

    float H = 0.f;
    const f32x4 z4 = {0.0f,0.0f,0.0f,0.0f};

    unsigned int  PAa = 0, PAb = 0, PAc = 0, PAd = 0;
    unsigned short PBa = 0, PBb = 0, PBc = 0, PBd = 0;
    LOADPF(PAa, PBa, 0);
    LOADPF(PAb, PBb, 1);
    LOADPF(PAc, PBc, 2);
    LOADPF(PAd, PBd, 3);
    __syncthreads();

    for (int t = 0; t < 256; t += 4) {
        STEP(&hAbuf[0][0], &hAbuf[1][0], PAa, PBa, t + 4);
        STEP(&hAbuf[1][0], &hAbuf[0][0], PAb, PBb, t + 5);
        STEP(&hAbuf[0][0], &hAbuf[1][0], PAc, PBc, t + 6);
        STEP(&hAbuf[1][0], &hAbuf[0][0], PAd, PBd, t + 7);
    }

    h_ws[(size_t)(b0 + l4)*128 + j] = H;
}

// ---------------- K3: proj + SDE, MFMA, 4 batches/block x 256 blocks (all CUs) ----------------
#define AFRAG(BUF, S, ks) (*(const short8*)((const char*)(BUF) + l15*(S) + ((((ks)*4 + l4) ^ (l15 & 7))*16)))
#define PF18(W, ks) (*(const short8*)((W) + (((size_t)(w*18 + (ks)))*64 + lane)*8))
#define PF4(W, ks)  (*(const short8*)((W) + (((size_t)(w*4 + (ks)))*64 + lane)*8))
#define PFW(W, tile, ks) (*(const short8*)((W) + (((size_t)((w*2 + (tile))*4 + (ks)))*64 + lane)*8))
#define HSTORE(BUF, bb, col, val) (*(unsigned short*)((char*)(BUF) + (bb)*256 + ((((col)>>3) ^ ((bb)&7))*16) + ((col)&7)*2) = f2bf(val))
#define MFMA16(af, bf, c) __builtin_amdgcn_mfma_f32_16x16x32_bf16((af), (bf), (c), 0, 0, 0)

__launch_bounds__(512, 1)
__global__ void sde_kernel(const float* __restrict__ ctx_ang,
                           const float* __restrict__ dW,
                           const float* __restrict__ proj_w,
                           const float* __restrict__ proj_b,
                           const float* __restrict__ dr_b0, const float* __restrict__ dr_b1,
                           const float* __restrict__ dr_b2, const float* __restrict__ dr_b3,
                           const float* __restrict__ df_b0, const float* __restrict__ df_b1,
                           const float* __restrict__ df_b2,
                           const unsigned short* __restrict__ W0d, const unsigned short* __restrict__ W1d,
                           const unsigned short* __restrict__ W2d, const unsigned short* __restrict__ W3d,
                           const unsigned short* __restrict__ W0f, const unsigned short* __restrict__ W1f,
                           const unsigned short* __restrict__ W2f,
                           const float* __restrict__ h_ws,
                           float* __restrict__ out) {
    __shared__ __align__(16) float th[4*256];
    __shared__ __align__(16) float ctxs[4*64];
    __shared__ __align__(16) float h32[4*128];
    __shared__ __align__(16) unsigned short inpA[16*576];
    __shared__ __align__(16) unsigned short hA[16*128], hB[16*128], hC[16*128], hD[16*128];

    const int tid  = threadIdx.x;
    const int lane = tid & 63;
    const int w    = tid >> 6;
    const int l15  = lane & 15;
    const int l4   = lane >> 4;
    const int b0   = blockIdx.x * 4;
    const f32x4 z4 = {0.f,0.f,0.f,0.f};

    h32[tid & 511] = 0.0f;
    __syncthreads();
    ((float*)h32)[tid] = h_ws[(size_t)b0*128 + tid];
    __syncthreads();
    if (tid < 256) {
        int b = tid >> 6, c = tid & 63;
        ctxs[tid] = proj_b[c] + dot4(proj_w + (size_t)c*128, h32 + b*128, 128);
    }
#pragma unroll
    for (int e = 0; e < 2; ++e) {
        int idx = tid + e*512; int b = idx >> 8, i = idx & 255;
        th[idx] = wrapf(ctx_ang[((size_t)(b0 + b)*256 + 255)*256 + i]);
    }

    const int j  = w*16 + l15;
    const int j20 = w*32 + l15;
    const int j21 = w*32 + 16 + l15;
    const float bd0 = dr_b0[j], bd1 = dr_b1[j], bd2 = dr_b2[j];
    const float bf0 = df_b0[j], bf1 = df_b1[j];
    const float bd3t0 = dr_b3[j20], bd3t1 = dr_b3[j21];
    const float bf2t0 = df_b2[j20], bf2t1 = df_b2[j21];
    __syncthreads();

    for (int k = 0; k < 5; ++k) {
#pragma unroll
        for (int e = 0; e < 5; ++e) {
            int idx = tid + e*512;
            if (idx < 2304) {
                int b = idx / 576;
                int i = idx - b*576;
                float vv;
                if (i < 256)      vv = __sinf(th[(b<<8) + i]);
                else if (i < 512) vv = __cosf(th[(b<<8) + i - 256]);
                else              vv = ctxs[(b<<6) + i - 512];
                *(unsigned short*)((char*)inpA + b*1152 + (((i>>3) ^ (b&7))*16) + (i&7)*2) = f2bf(vv);
            }
        }
        __syncthreads();

        // p1: drift L0 || diff L0, K=576
        {
            f32x4 a0=z4,a1=z4,c0=z4,c1=z4;
#pragma unroll
            for (int ks = 0; ks < 18; ks += 2) {
                short8 af0 = AFRAG(inpA, 1152, ks);
                short8 af1 = AFRAG(inpA, 1152, ks+1);
                a0 = MFMA16(af0, PF18(W0d, ks),   a0);
                c0 = MFMA16(af0, PF18(W0f, ks),   c0);
                a1 = MFMA16(af1, PF18(W0d, ks+1), a1);
                c1 = MFMA16(af1, PF18(W0f, ks+1), c1);
            }
#pragma unroll
            for (int r = 0; r < 4; ++r) {
                int bb = l4*4 + r;
                HSTORE(hA, bb, j, siluf(a0[r] + a1[r] + bd0));
                HSTORE(hC, bb, j, siluf(c0[r] + c1[r] + bf0));
            }
        }
        __syncthreads();

        // p2: drift L1 || diff L1, K=128
        {
            f32x4 a0=z4,a1=z4,c0=z4,c1=z4;
#pragma unroll
            for (int ks = 0; ks < 4; ks += 2) {
                short8 aA0 = AFRAG(hA, 256, ks), aA1 = AFRAG(hA, 256, ks+1);
                short8 aC0 = AFRAG(hC, 256, ks), aC1 = AFRAG(hC, 256, ks+1);
                a0 = MFMA16(aA0, PF4(W1d, ks),   a0);
                c0 = MFMA16(aC0, PF4(W1f, ks),   c0);
                a1 = MFMA16(aA1, PF4(W1d, ks+1), a1);
                c1 = MFMA16(aC1, PF4(W1f, ks+1), c1);
            }
#pragma unroll
            for (int r = 0; r < 4; ++r) {
                int bb = l4*4 + r;
                HSTORE(hB, bb, j, siluf(a0[r] + a1[r] + bd1));
                HSTORE(hD, bb, j, siluf(c0[r] + c1[r] + bf1));
            }
        }
        __syncthreads();

        // p3: drift L2 || diff L2 (N=256), K=128; sg kept in REGISTERS
        float sgr[2][4];
        {
            f32x4 a0=z4,a1=z4,s0=z4,s1=z4,s2=z4,s3=z4;
#pragma unroll
            for (int ks = 0; ks < 4; ks += 2) {
                short8 b0f = AFRAG(hB, 256, ks), b1f = AFRAG(hB, 256, ks+1);
                short8 d0f = AFRAG(hD, 256, ks), d1f = AFRAG(hD, 256, ks+1);
                a0 = MFMA16(b0f, PF4(W2d, ks),   a0);
                a1 = MFMA16(b1f, PF4(W2d, ks+1), a1);
                s0 = MFMA16(d0f, PFW(W2f, 0, ks),   s0);
                s1 = MFMA16(d1f, PFW(W2f, 0, ks+1), s1);
                s2 = MFMA16(d0f, PFW(W2f, 1, ks),   s2);
                s3 = MFMA16(d1f, PFW(W2f, 1, ks+1), s3);
            }
#pragma unroll
            for (int r = 0; r < 4; ++r) {
                int bb = l4*4 + r;
                HSTORE(hA, bb, j, siluf(a0[r] + a1[r] + bd2));
                float aa0 = s0[r] + s1[r] + bf2t0;
                float aa1 = s2[r] + s3[r] + bf2t1;
                float sp0 = (aa0 > 15.f) ? aa0 : log1pf(__expf(aa0));
                float sp1 = (aa1 > 15.f) ? aa1 : log1pf(__expf(aa1));
                sgr[0][r] = sp0 * DIFF_SCALE_F;
                sgr[1][r] = sp1 * DIFF_SCALE_F;
            }
        }
        __syncthreads();

        // p4: drift L3 (N=256), K=128; theta update (only l4==0 lanes own valid rows 0-3)
        {
            f32x4 m0=z4,m1=z4,m2=z4,m3=z4;
#pragma unroll
            for (int ks = 0; ks < 4; ks += 2) {
                short8 h0f = AFRAG(hA, 256, ks), h1f = AFRAG(hA, 256, ks+1);
                m0 = MFMA16(h0f, PFW(W3d, 0, ks),   m0);
                m1 = MFMA16(h1f, PFW(W3d, 0, ks+1), m1);
                m2 = MFMA16(h0f, PFW(W3d, 1, ks),   m2);
                m3 = MFMA16(h1f, PFW(W3d, 1, ks+1), m3);
            }
            if (l4 == 0) {
#pragma unroll
                for (int r = 0; r < 4; ++r) {
                    int bb = r;
                    {
                        float mu = m0[r] + m1[r] + bd3t0;
                        float dw = dW[((size_t)(b0 + bb)*5 + k)*256 + j20];
                        th[(bb<<8) + j20] = wrapf(th[(bb<<8) + j20] + mu*DT_F + sgr[0][r]*dw);
                    }
                    {
                        float mu = m2[r] + m3[r] + bd3t1;
                        float dw = dW[((size_t)(b0 + bb)*5 + k)*256 + j21];
                        th[(bb<<8) + j21] = wrapf(th[(bb<<8) + j21] + mu*DT_F + sgr[1][r]*dw);
                    }
                }
            }
        }
        __syncthreads();
    }

#pragma unroll
    for (int e = 0; e < 2; ++e) {
        int idx = tid + e*512;
        out[(size_t)b0*256 + idx] = th[idx];
    }
}

extern "C" void kernel_launch(void* const* d_in, const int* in_sizes, int n_in,
                              void* d_out, int out_size, void* d_ws, size_t ws_size,
                              hipStream_t stream) {
    const float* ctx_ang = (const float*)d_in[0];
    const float* dW      = (const float*)d_in[1];
    const float* wih     = (const float*)d_in[2];
    const float* whh     = (const float*)d_in[3];
    const float* gru_b   = (const float*)d_in[4];
    const float* gru_bn  = (const float*)d_in[5];
    const float* proj_w  = (const float*)d_in[6];
    const float* proj_b  = (const float*)d_in[7];
    const float* dr_w0   = (const float*)d_in[8];
    const float* dr_b0   = (const float*)d_in[9];
    const float* dr_w1   = (const float*)d_in[10];
    const float* dr_b1   = (const float*)d_in[11];
    const float* dr_w2   = (const float*)d_in[12];
    const float* dr_b2   = (const float*)d_in[13];
    const float* dr_w3   = (const float*)d_in[14];
    const float* dr_b3   = (const float*)d_in[15];
    const float* df_w0   = (const float*)d_in[16];
    const float* df_b0   = (const float*)d_in[17];
    const float* df_w1   = (const float*)d_in[18];
    const float* df_b1   = (const float*)d_in[19];
    const float* df_w2   = (const float*)d_in[20];
    const float* df_b2   = (const float*)d_in[21];
    float* out = (float*)d_out;

    char* ws = (char*)d_ws;
    unsigned int*   P01  = (unsigned int*)ws;                         // 134,217,728 B
    unsigned short* P2   = (unsigned short*)(ws + 134217728);         //  67,108,864 B
    unsigned short* wihp = (unsigned short*)(ws + 201326592);         //     393,216 B (packed)
    unsigned short* whhb = (unsigned short*)(ws + 201719808);         //      98,304 B
    float*          h_ws = (float*)(ws + 201818112);                  //     524,288 B

    unsigned short* Wb  = (unsigned short*)ws;   // dead P01 region after scan
    unsigned short* W0d = Wb;
    unsigned short* W1d = Wb + 73728;
    unsigned short* W2d = Wb + 90112;
    unsigned short* W3d = Wb + 106496;
    unsigned short* W0f = Wb + 139264;
    unsigned short* W1f = Wb + 212992;
    unsigned short* W2f = Wb + 229376;

    prep_kernel<<<768, 256, 0, stream>>>(wih, whh, wihp, whhb);
    gi_gemm_kernel<<<8192, 256, 0, stream>>>(ctx_ang, wihp, P01, P2);
    scan_kernel<<<256, 512, 0, stream>>>(P01, P2, whhb, gru_b, gru_bn, h_ws);
    prep2_kernel<<<1024, 256, 0, stream>>>(dr_w0, dr_w1, dr_w2, dr_w3, df_w0, df_w1, df_w2, Wb);
    sde_kernel<<<256, 512, 0, stream>>>(ctx_ang, dW,
        proj_w, proj_b, dr_b0, dr_b1, dr_b2, dr_b3, df_b0, df_b1, df_b2,
        W0d, W1d, W2d, W3d, W0f, W1f, W2f, h_ws, out);
}